// Round 1
// baseline (403.550 us; speedup 1.0000x reference)
//
#include <hip/hip_runtime.h>
#include <hip/hip_bf16.h>

#define NN 320
#define CC 128
#define HH 4
#define CHD 32
#define HC 128
#define NP (NN*NN)

typedef __hip_bfloat16 bf16;
typedef __bf16 bfv8 __attribute__((ext_vector_type(8)));
typedef float fv4 __attribute__((ext_vector_type(4)));

__device__ __forceinline__ unsigned short bfbits(float f) {
    bf16 h = __float2bfloat16(f);
    return *reinterpret_cast<unsigned short*>(&h);
}

// ---------------- K0: weight convert/transpose to bf16 ----------------
__global__ __launch_bounds__(256) void k_wconv(
    const float* __restrict__ wq, const float* __restrict__ wk,
    const float* __restrict__ wv, const float* __restrict__ wg,
    const float* __restrict__ wo, const float* __restrict__ w_bias,
    bf16* __restrict__ wt, bf16* __restrict__ wot, bf16* __restrict__ wtb)
{
    __shared__ unsigned short T[128 * 136];
    const int b = blockIdx.x, t = threadIdx.x;
    if (b < 5) {
        const float* W = (b == 0) ? wq : (b == 1) ? wk : (b == 2) ? wv : (b == 3) ? wg : wo;
        bf16* D = (b < 4) ? (wt + b * 16384) : wot;
        const float scale = (b == 0) ? 0.17677669529663687f : 1.0f;
        for (int idx = t; idx < 16384; idx += 256) {
            int c = idx >> 7, out = idx & 127;
            T[out * 136 + c] = bfbits(W[idx] * scale);
        }
        __syncthreads();
        for (int i8 = t; i8 < 2048; i8 += 256) {
            int out = i8 >> 4, c0 = (i8 & 15) * 8;
            uint4 v = *reinterpret_cast<const uint4*>(&T[out * 136 + c0]);
            *reinterpret_cast<uint4*>(D + out * 128 + c0) = v;
        }
    } else {
        int out = t >> 4, c0 = (t & 15) * 8;
        unsigned short vals[8];
#pragma unroll
        for (int j = 0; j < 8; j++)
            vals[j] = (out < 4) ? bfbits(w_bias[(c0 + j) * 4 + out]) : (unsigned short)0;
        *reinterpret_cast<uint4*>(wtb + out * 128 + c0) = *reinterpret_cast<uint4*>(vals);
    }
}

// ---------------- K1: LN + MFMA projections + tri_bias ----------------
__global__ __launch_bounds__(256) void k_proj(
    const float* __restrict__ x, const float* __restrict__ ln_g, const float* __restrict__ ln_b,
    const bf16* __restrict__ wt, const bf16* __restrict__ wtb, const float* __restrict__ bg,
    bf16* __restrict__ qo, bf16* __restrict__ ko, bf16* __restrict__ vo, bf16* __restrict__ go,
    float* __restrict__ tri)
{
    __shared__ unsigned short A[128 * 136];   // LN(x) bf16, [pixel][c], pad 8
    const int t = threadIdx.x;
    const int wv = t >> 6, lane = t & 63, g = lane >> 4, c = lane & 15;
    const size_t pb = (size_t)blockIdx.x * 128;

    // ---- LayerNorm in registers: 4 threads per pixel, 2 rounds ----
#pragma unroll
    for (int rnd = 0; rnd < 2; rnd++) {
        const int p = (t >> 2) + rnd * 64, l = t & 3;
        const float* xr = x + (pb + p) * CC + l * 32;
        float4 xv[8];
#pragma unroll
        for (int i = 0; i < 8; i++) xv[i] = reinterpret_cast<const float4*>(xr)[i];
        float s = 0.f, s2 = 0.f;
#pragma unroll
        for (int i = 0; i < 8; i++) {
            s  += xv[i].x + xv[i].y + xv[i].z + xv[i].w;
            s2 += xv[i].x * xv[i].x + xv[i].y * xv[i].y + xv[i].z * xv[i].z + xv[i].w * xv[i].w;
        }
        s  += __shfl_xor(s, 1, 4);  s  += __shfl_xor(s, 2, 4);
        s2 += __shfl_xor(s2, 1, 4); s2 += __shfl_xor(s2, 2, 4);
        float mu = s * (1.f / CC);
        float var = s2 * (1.f / CC) - mu * mu;
        float rstd = rsqrtf(var + 1e-5f);
        const float4* gr = reinterpret_cast<const float4*>(ln_g + l * 32);
        const float4* br = reinterpret_cast<const float4*>(ln_b + l * 32);
#pragma unroll
        for (int i = 0; i < 8; i += 2) {
            float4 g0 = gr[i], g1 = gr[i + 1], b0 = br[i], b1 = br[i + 1];
            uint4 pk;
            pk.x = (unsigned)bfbits((xv[i].x - mu) * rstd * g0.x + b0.x)
                 | ((unsigned)bfbits((xv[i].y - mu) * rstd * g0.y + b0.y) << 16);
            pk.y = (unsigned)bfbits((xv[i].z - mu) * rstd * g0.z + b0.z)
                 | ((unsigned)bfbits((xv[i].w - mu) * rstd * g0.w + b0.w) << 16);
            pk.z = (unsigned)bfbits((xv[i+1].x - mu) * rstd * g1.x + b1.x)
                 | ((unsigned)bfbits((xv[i+1].y - mu) * rstd * g1.y + b1.y) << 16);
            pk.w = (unsigned)bfbits((xv[i+1].z - mu) * rstd * g1.z + b1.z)
                 | ((unsigned)bfbits((xv[i+1].w - mu) * rstd * g1.w + b1.w) << 16);
            *reinterpret_cast<uint4*>(&A[p * 136 + l * 32 + i * 4]) = pk;
        }
    }
    __syncthreads();

    // ---- pixel fragments: 2 tiles of 16 pixels per wave ----
    bfv8 bx[2][4];
#pragma unroll
    for (int tile = 0; tile < 2; tile++)
#pragma unroll
        for (int kc = 0; kc < 4; kc++)
            bx[tile][kc] = *reinterpret_cast<const bfv8*>(
                &A[(wv * 32 + tile * 16 + c) * 136 + kc * 32 + 8 * g]);

    fv4 zero = {0.f, 0.f, 0.f, 0.f};

    // ---- tri bias: A=pixels, B=w_bias^T (D col = head) ----
    {
        fv4 at0 = zero, at1 = zero;
#pragma unroll
        for (int kc = 0; kc < 4; kc++) {
            bfv8 bb = *reinterpret_cast<const bfv8*>(wtb + c * 128 + kc * 32 + 8 * g);
            at0 = __builtin_amdgcn_mfma_f32_16x16x32_bf16(bx[0][kc], bb, at0, 0, 0, 0);
            at1 = __builtin_amdgcn_mfma_f32_16x16x32_bf16(bx[1][kc], bb, at1, 0, 0, 0);
        }
        if (c < HH) {
            float4 s0 = {at0[0], at0[1], at0[2], at0[3]};
            float4 s1 = {at1[0], at1[1], at1[2], at1[3]};
            float* tb = tri + (size_t)c * NP + pb + wv * 32 + 4 * g;
            *reinterpret_cast<float4*>(tb)      = s0;
            *reinterpret_cast<float4*>(tb + 16) = s1;
        }
    }

    // ---- q,k,v,g projections: A=weights, B=pixels ----
    bf16* Os[4] = {qo, ko, vo, go};
#pragma unroll 1
    for (int m = 0; m < 4; m++) {
        const bf16* WtM = wt + m * 16384;
        fv4 acc[2][8];
#pragma unroll
        for (int n = 0; n < 8; n++) { acc[0][n] = zero; acc[1][n] = zero; }
#pragma unroll
        for (int n = 0; n < 8; n++)
#pragma unroll
            for (int kc = 0; kc < 4; kc++) {
                bfv8 bw = *reinterpret_cast<const bfv8*>(WtM + (n * 16 + c) * 128 + kc * 32 + 8 * g);
                acc[0][n] = __builtin_amdgcn_mfma_f32_16x16x32_bf16(bw, bx[0][kc], acc[0][n], 0, 0, 0);
                acc[1][n] = __builtin_amdgcn_mfma_f32_16x16x32_bf16(bw, bx[1][kc], acc[1][n], 0, 0, 0);
            }
        if (m == 3) {
#pragma unroll
            for (int n = 0; n < 8; n++) {
                float4 bgv = *reinterpret_cast<const float4*>(bg + n * 16 + 4 * g);
                float bgs[4] = {bgv.x, bgv.y, bgv.z, bgv.w};
#pragma unroll
                for (int tile = 0; tile < 2; tile++)
#pragma unroll
                    for (int r = 0; r < 4; r++) {
                        float z = acc[tile][n][r] + bgs[r];
                        acc[tile][n][r] = 1.f / (1.f + __expf(-z));
                    }
            }
        }
        bf16* O = Os[m];
#pragma unroll
        for (int tile = 0; tile < 2; tile++)
#pragma unroll
            for (int n = 0; n < 8; n++) {
                uint2 pk;
                pk.x = (unsigned)bfbits(acc[tile][n][0]) | ((unsigned)bfbits(acc[tile][n][1]) << 16);
                pk.y = (unsigned)bfbits(acc[tile][n][2]) | ((unsigned)bfbits(acc[tile][n][3]) << 16);
                *reinterpret_cast<uint2*>(O + (pb + wv * 32 + tile * 16 + c) * HC + n * 16 + 4 * g) = pk;
            }
    }
}

// ---------------- K2: MFMA attention ----------------
// Changes vs prev: (a) P relayout done in-register via 2-round butterfly
//     (shfl_xor 32 then 16) -> no 42KB P LDS, occupancy 2->4 blocks/CU.
// (b) Vt staged as packed key-pair words with XOR bank swizzle
//     (col_word ^ 4*(d&7) ^ 8*(d>>3), 192-word rows) -> write conflicts 8-way->2-way.
// (c) 1-D grid with bijective XCD remap: the 5 q-tiles sharing one (i,h)
//     K/V row get the same id%8 -> same XCD L2.
__global__ __launch_bounds__(256, 4) void k_attn(
    const bf16* __restrict__ qi, const bf16* __restrict__ ki, const bf16* __restrict__ vi,
    const bf16* __restrict__ gi, const float* __restrict__ mask, const float* __restrict__ tri,
    bf16* __restrict__ oo)
{
    __shared__ unsigned VtW[32 * 192];   // 24576 B, swizzled V^T (word = 2 keys)

    const int t = threadIdx.x;
    const int w = t >> 6, lane = t & 63, g = lane >> 4, c = lane & 15;

    // XCD-aware bijective remap: id = r + 8*(ih_hi*5 + qb5), ih = ih_hi*8 + r
    const int r_ = blockIdx.x & 7, pos = blockIdx.x >> 3;
    const int qb5 = pos % 5;
    const int ihh = (pos / 5) * 8 + r_;
    const int h = ihh & 3, i = ihh >> 2;
    const int qb = qb5 * 64 + w * 16;
    const size_t rowbase = (size_t)i * NN;

    // ---- stage V: thread = (key-pair, d-octet); packed b32 writes, swizzled ----
#pragma unroll
    for (int it = 0; it < 3; it++) {
        int idx = it * 256 + t;
        if (idx < 640) {
            int kp = idx >> 2, oct = idx & 3, d0 = oct * 8;
            const uint4 va = *reinterpret_cast<const uint4*>(vi + (rowbase + 2 * kp) * HC + h * CHD + d0);
            const uint4 vb = *reinterpret_cast<const uint4*>(vi + (rowbase + 2 * kp + 1) * HC + h * CHD + d0);
            unsigned a4[4] = {va.x, va.y, va.z, va.w};
            unsigned b4[4] = {vb.x, vb.y, vb.z, vb.w};
#pragma unroll
            for (int u2 = 0; u2 < 4; u2++) {
                int d_e = d0 + 2 * u2, d_o = d_e + 1;
                unsigned we = (a4[u2] & 0xffffu) | ((b4[u2] & 0xffffu) << 16);
                unsigned wo = (a4[u2] >> 16)     | ((b4[u2] >> 16) << 16);
                VtW[d_e * 192 + (kp ^ (4 * (d_e & 7)) ^ (8 * (d_e >> 3)))] = we;
                VtW[d_o * 192 + (kp ^ (4 * (d_o & 7)) ^ (8 * (d_o >> 3)))] = wo;
            }
        }
    }

    bfv8 bq = *reinterpret_cast<const bfv8*>(qi + (rowbase + qb + c) * HC + h * CHD + 8 * g);

    const float* maskrow = mask + (size_t)i * NN;
    const float* trirow  = tri + (size_t)h * NP + (size_t)(qb + c) * NN;
    fv4 zero = {0.f, 0.f, 0.f, 0.f};

    // ---- scores: lane (g,c) holds s[kt][r] = P[k=16kt+4g+r][q=c] ----
    float s[20][4];
#pragma unroll
    for (int kt = 0; kt < 20; kt++) {
        int kbase = kt * 16;
        bfv8 ak = *reinterpret_cast<const bfv8*>(ki + (rowbase + kbase + c) * HC + h * CHD + 8 * g);
        fv4 sa = __builtin_amdgcn_mfma_f32_16x16x32_bf16(ak, bq, zero, 0, 0, 0);
        float4 mk = *reinterpret_cast<const float4*>(maskrow + kbase + 4 * g);
        float4 tr = *reinterpret_cast<const float4*>(trirow + kbase + 4 * g);
        float mks[4] = {mk.x, mk.y, mk.z, mk.w};
        float trs[4] = {tr.x, tr.y, tr.z, tr.w};
#pragma unroll
        for (int r = 0; r < 4; r++) {
            float bias = 1.0e9f * (mks[r] - 1.0f);
            s[kt][r] = sa[r] + trs[r] + bias;
        }
    }

    // ---- softmax over k (rows of P live across g-groups + c fixed q) ----
    float mx = -3.0e38f;
#pragma unroll
    for (int kt = 0; kt < 20; kt++)
#pragma unroll
        for (int r = 0; r < 4; r++) mx = fmaxf(mx, s[kt][r]);
    mx = fmaxf(mx, __shfl_xor(mx, 16, 64));
    mx = fmaxf(mx, __shfl_xor(mx, 32, 64));
    float sm = 0.f;
#pragma unroll
    for (int kt = 0; kt < 20; kt++)
#pragma unroll
        for (int r = 0; r < 4; r++) {
            float e = __expf(s[kt][r] - mx);
            s[kt][r] = e;
            sm += e;
        }
    sm += __shfl_xor(sm, 16, 64);
    sm += __shfl_xor(sm, 32, 64);
    float linv = 1.f / sm;

    // ---- pack P to bf16 pairs in registers; s dies here ----
    unsigned W[20][2];
#pragma unroll
    for (int kt = 0; kt < 20; kt++) {
        W[kt][0] = (unsigned)bfbits(s[kt][0]) | ((unsigned)bfbits(s[kt][1]) << 16);
        W[kt][1] = (unsigned)bfbits(s[kt][2]) | ((unsigned)bfbits(s[kt][3]) << 16);
    }

    __syncthreads();   // Vt staged (cross-wave)

    // ---- PV: butterfly relayout (lane^32 then lane^16) + swizzled Vt reads ----
    const int xsw0 = (4 * (c & 7)) ^ (8 * (c >> 3));
    const int xsw1 = (4 * (c & 7)) ^ (8 * ((16 + c) >> 3));
    const unsigned* VtR0 = &VtW[c * 192];
    const unsigned* VtR1 = &VtW[(16 + c) * 192];
    const int p = ((g >> 1) ^ g) & 1;
    fv4 o0 = zero, o1 = zero;
#pragma unroll
    for (int ks = 0; ks < 10; ks++) {
        unsigned A0 = W[2 * ks][0],     A1 = W[2 * ks][1];
        unsigned B0 = W[2 * ks + 1][0], B1 = W[2 * ks + 1][1];
        // step 1: keep own-tile words, exchange other-tile across lane^32
        unsigned K0 = (g & 2) ? B0 : A0, K1 = (g & 2) ? B1 : A1;
        unsigned S0 = (g & 2) ? A0 : B0, S1 = (g & 2) ? A1 : B1;
        unsigned R0 = __shfl_xor(S0, 32), R1 = __shfl_xor(S1, 32);
        // step 2: exchange across lane^16; parity picks which word travels
        unsigned sent0 = p ? K0 : R0, sent1 = p ? K1 : R1;
        unsigned kept0 = p ? R0 : K0, kept1 = p ? R1 : K1;
        unsigned t0 = __shfl_xor(sent0, 16), t1 = __shfl_xor(sent1, 16);
        union { unsigned u[4]; bfv8 v; } uu;
        uu.u[0] = (g & 1) ? t0 : kept0;
        uu.u[1] = (g & 1) ? t1 : kept1;
        uu.u[2] = (g & 1) ? kept0 : t0;
        uu.u[3] = (g & 1) ? kept1 : t1;
        bfv8 bp = uu.v;

        int col = 16 * ks + 4 * g;
        bfv8 av0 = *reinterpret_cast<const bfv8*>(VtR0 + (col ^ xsw0));
        bfv8 av1 = *reinterpret_cast<const bfv8*>(VtR1 + (col ^ xsw1));
        o0 = __builtin_amdgcn_mfma_f32_16x16x32_bf16(av0, bp, o0, 0, 0, 0);
        o1 = __builtin_amdgcn_mfma_f32_16x16x32_bf16(av1, bp, o1, 0, 0, 0);
    }

    size_t obase = (rowbase + qb + c) * HC + h * CHD;
#pragma unroll
    for (int mt = 0; mt < 2; mt++) {
        fv4 oc = mt ? o1 : o0;
        int d0 = mt * 16 + 4 * g;
        uint2 gg = *reinterpret_cast<const uint2*>(gi + obase + d0);
        float gf0 = __uint_as_float(gg.x << 16);
        float gf1 = __uint_as_float(gg.x & 0xffff0000u);
        float gf2 = __uint_as_float(gg.y << 16);
        float gf3 = __uint_as_float(gg.y & 0xffff0000u);
        uint2 st;
        st.x = (unsigned)bfbits(oc[0] * linv * gf0) | ((unsigned)bfbits(oc[1] * linv * gf1) << 16);
        st.y = (unsigned)bfbits(oc[2] * linv * gf2) | ((unsigned)bfbits(oc[3] * linv * gf3) << 16);
        *reinterpret_cast<uint2*>(oo + obase + d0) = st;
    }
}

// ---------------- K3: MFMA output projection (fp32 out, float4 stores) ----------------
__global__ __launch_bounds__(256) void k_out(
    const bf16* __restrict__ oi, const bf16* __restrict__ wot, const float* __restrict__ bo,
    float* __restrict__ outp)
{
    const int t = threadIdx.x;
    const int wv = t >> 6, lane = t & 63, g = lane >> 4, c = lane & 15;
    const size_t pb = (size_t)blockIdx.x * 64;

    bfv8 bx[4];
#pragma unroll
    for (int kc = 0; kc < 4; kc++)
        bx[kc] = *reinterpret_cast<const bfv8*>(oi + (pb + wv * 16 + c) * HC + kc * 32 + 8 * g);

    fv4 zero = {0.f, 0.f, 0.f, 0.f};
    fv4 acc[8];
#pragma unroll
    for (int n = 0; n < 8; n++) acc[n] = zero;
#pragma unroll
    for (int n = 0; n < 8; n++)
#pragma unroll
        for (int kc = 0; kc < 4; kc++) {
            bfv8 bw = *reinterpret_cast<const bfv8*>(wot + (n * 16 + c) * 128 + kc * 32 + 8 * g);
            acc[n] = __builtin_amdgcn_mfma_f32_16x16x32_bf16(bw, bx[kc], acc[n], 0, 0, 0);
        }
#pragma unroll
    for (int n = 0; n < 8; n++) {
        float4 b4 = *reinterpret_cast<const float4*>(bo + n * 16 + 4 * g);
        float4 st;
        st.x = acc[n][0] + b4.x;
        st.y = acc[n][1] + b4.y;
        st.z = acc[n][2] + b4.z;
        st.w = acc[n][3] + b4.w;
        *reinterpret_cast<float4*>(outp + (pb + wv * 16 + c) * CC + n * 16 + 4 * g) = st;
    }
}

extern "C" void kernel_launch(void* const* d_in, const int* in_sizes, int n_in,
                              void* d_out, int out_size, void* d_ws, size_t ws_size,
                              hipStream_t stream) {
    const float* x      = (const float*)d_in[0];
    const float* mask   = (const float*)d_in[1];
    const float* ln_g   = (const float*)d_in[2];
    const float* ln_b   = (const float*)d_in[3];
    const float* w_bias = (const float*)d_in[4];
    const float* wq     = (const float*)d_in[5];
    const float* wk     = (const float*)d_in[6];
    const float* wv     = (const float*)d_in[7];
    const float* wg     = (const float*)d_in[8];
    const float* bg     = (const float*)d_in[9];
    const float* wo     = (const float*)d_in[10];
    const float* bo     = (const float*)d_in[11];
    float* outp = (float*)d_out;

    bf16* qws = (bf16*)d_ws;
    bf16* kws = qws + (size_t)NP*HC;
    bf16* vws = kws + (size_t)NP*HC;
    bf16* gws = vws + (size_t)NP*HC;
    bf16* ows = gws + (size_t)NP*HC;
    float* tri = (float*)(ows + (size_t)NP*HC);
    bf16* wt  = (bf16*)(tri + (size_t)NP*HH);
    bf16* wot = wt + 4 * 16384;
    bf16* wtb = wot + 16384;

    hipLaunchKernelGGL(k_wconv, dim3(6), dim3(256), 0, stream,
                       wq, wk, wv, wg, wo, w_bias, wt, wot, wtb);
    hipLaunchKernelGGL(k_proj, dim3(NP/128), dim3(256), 0, stream,
                       x, ln_g, ln_b, wt, wtb, bg, qws, kws, vws, gws, tri);
    hipLaunchKernelGGL(k_attn, dim3(6400), dim3(256), 0, stream,
                       qws, kws, vws, gws, mask, tri, ows);
    hipLaunchKernelGGL(k_out, dim3(NP/64), dim3(256), 0, stream,
                       ows, wot, bo, outp);
}

// Round 2
// 392.509 us; speedup vs baseline: 1.0281x; 1.0281x over previous
//
#include <hip/hip_runtime.h>
#include <hip/hip_bf16.h>

#define NN 320
#define CC 128
#define HH 4
#define CHD 32
#define HC 128
#define NP (NN*NN)

typedef __hip_bfloat16 bf16;
typedef __bf16 bfv8 __attribute__((ext_vector_type(8)));
typedef short bsv4 __attribute__((ext_vector_type(4)));
typedef float fv4 __attribute__((ext_vector_type(4)));

__device__ __forceinline__ unsigned short bfbits(float f) {
    bf16 h = __float2bfloat16(f);
    return *reinterpret_cast<unsigned short*>(&h);
}

// 16x16x16 bf16 MFMA (K=16): B-frag layout B[k=4g+i][n=c] matches the QK
// D-layout S[k=4g+r][q=c] exactly -> P feeds PV straight from registers.
// Emitted via inline asm (cdna4_isa.md §10: A=2, B=2, C/D=4 regs).
__device__ __forceinline__ fv4 mfma16x16x16(bsv4 a, bsv4 b, fv4 c) {
    asm("v_mfma_f32_16x16x16_bf16 %0, %1, %2, %0" : "+v"(c) : "v"(a), "v"(b));
    return c;
}

// ---------------- K0: weight convert/transpose to bf16 ----------------
__global__ __launch_bounds__(256) void k_wconv(
    const float* __restrict__ wq, const float* __restrict__ wk,
    const float* __restrict__ wv, const float* __restrict__ wg,
    const float* __restrict__ wo, const float* __restrict__ w_bias,
    bf16* __restrict__ wt, bf16* __restrict__ wot, bf16* __restrict__ wtb)
{
    __shared__ unsigned short T[128 * 136];
    const int b = blockIdx.x, t = threadIdx.x;
    if (b < 5) {
        const float* W = (b == 0) ? wq : (b == 1) ? wk : (b == 2) ? wv : (b == 3) ? wg : wo;
        bf16* D = (b < 4) ? (wt + b * 16384) : wot;
        const float scale = (b == 0) ? 0.17677669529663687f : 1.0f;
        for (int idx = t; idx < 16384; idx += 256) {
            int c = idx >> 7, out = idx & 127;
            T[out * 136 + c] = bfbits(W[idx] * scale);
        }
        __syncthreads();
        for (int i8 = t; i8 < 2048; i8 += 256) {
            int out = i8 >> 4, c0 = (i8 & 15) * 8;
            uint4 v = *reinterpret_cast<const uint4*>(&T[out * 136 + c0]);
            *reinterpret_cast<uint4*>(D + out * 128 + c0) = v;
        }
    } else {
        int out = t >> 4, c0 = (t & 15) * 8;
        unsigned short vals[8];
#pragma unroll
        for (int j = 0; j < 8; j++)
            vals[j] = (out < 4) ? bfbits(w_bias[(c0 + j) * 4 + out]) : (unsigned short)0;
        *reinterpret_cast<uint4*>(wtb + out * 128 + c0) = *reinterpret_cast<uint4*>(vals);
    }
}

// ---------------- K1: LN + MFMA projections + tri_bias ----------------
__global__ __launch_bounds__(256) void k_proj(
    const float* __restrict__ x, const float* __restrict__ ln_g, const float* __restrict__ ln_b,
    const bf16* __restrict__ wt, const bf16* __restrict__ wtb, const float* __restrict__ bg,
    bf16* __restrict__ qo, bf16* __restrict__ ko, bf16* __restrict__ vo, bf16* __restrict__ go,
    float* __restrict__ tri)
{
    __shared__ unsigned short A[128 * 136];   // LN(x) bf16, [pixel][c], pad 8
    const int t = threadIdx.x;
    const int wv = t >> 6, lane = t & 63, g = lane >> 4, c = lane & 15;
    const size_t pb = (size_t)blockIdx.x * 128;

    // ---- LayerNorm in registers: 4 threads per pixel, 2 rounds ----
#pragma unroll
    for (int rnd = 0; rnd < 2; rnd++) {
        const int p = (t >> 2) + rnd * 64, l = t & 3;
        const float* xr = x + (pb + p) * CC + l * 32;
        float4 xv[8];
#pragma unroll
        for (int i = 0; i < 8; i++) xv[i] = reinterpret_cast<const float4*>(xr)[i];
        float s = 0.f, s2 = 0.f;
#pragma unroll
        for (int i = 0; i < 8; i++) {
            s  += xv[i].x + xv[i].y + xv[i].z + xv[i].w;
            s2 += xv[i].x * xv[i].x + xv[i].y * xv[i].y + xv[i].z * xv[i].z + xv[i].w * xv[i].w;
        }
        s  += __shfl_xor(s, 1, 4);  s  += __shfl_xor(s, 2, 4);
        s2 += __shfl_xor(s2, 1, 4); s2 += __shfl_xor(s2, 2, 4);
        float mu = s * (1.f / CC);
        float var = s2 * (1.f / CC) - mu * mu;
        float rstd = rsqrtf(var + 1e-5f);
        const float4* gr = reinterpret_cast<const float4*>(ln_g + l * 32);
        const float4* br = reinterpret_cast<const float4*>(ln_b + l * 32);
#pragma unroll
        for (int i = 0; i < 8; i += 2) {
            float4 g0 = gr[i], g1 = gr[i + 1], b0 = br[i], b1 = br[i + 1];
            uint4 pk;
            pk.x = (unsigned)bfbits((xv[i].x - mu) * rstd * g0.x + b0.x)
                 | ((unsigned)bfbits((xv[i].y - mu) * rstd * g0.y + b0.y) << 16);
            pk.y = (unsigned)bfbits((xv[i].z - mu) * rstd * g0.z + b0.z)
                 | ((unsigned)bfbits((xv[i].w - mu) * rstd * g0.w + b0.w) << 16);
            pk.z = (unsigned)bfbits((xv[i+1].x - mu) * rstd * g1.x + b1.x)
                 | ((unsigned)bfbits((xv[i+1].y - mu) * rstd * g1.y + b1.y) << 16);
            pk.w = (unsigned)bfbits((xv[i+1].z - mu) * rstd * g1.z + b1.z)
                 | ((unsigned)bfbits((xv[i+1].w - mu) * rstd * g1.w + b1.w) << 16);
            *reinterpret_cast<uint4*>(&A[p * 136 + l * 32 + i * 4]) = pk;
        }
    }
    __syncthreads();

    // ---- pixel fragments: 2 tiles of 16 pixels per wave ----
    bfv8 bx[2][4];
#pragma unroll
    for (int tile = 0; tile < 2; tile++)
#pragma unroll
        for (int kc = 0; kc < 4; kc++)
            bx[tile][kc] = *reinterpret_cast<const bfv8*>(
                &A[(wv * 32 + tile * 16 + c) * 136 + kc * 32 + 8 * g]);

    fv4 zero = {0.f, 0.f, 0.f, 0.f};

    // ---- tri bias: A=pixels, B=w_bias^T (D col = head) ----
    {
        fv4 at0 = zero, at1 = zero;
#pragma unroll
        for (int kc = 0; kc < 4; kc++) {
            bfv8 bb = *reinterpret_cast<const bfv8*>(wtb + c * 128 + kc * 32 + 8 * g);
            at0 = __builtin_amdgcn_mfma_f32_16x16x32_bf16(bx[0][kc], bb, at0, 0, 0, 0);
            at1 = __builtin_amdgcn_mfma_f32_16x16x32_bf16(bx[1][kc], bb, at1, 0, 0, 0);
        }
        if (c < HH) {
            float4 s0 = {at0[0], at0[1], at0[2], at0[3]};
            float4 s1 = {at1[0], at1[1], at1[2], at1[3]};
            float* tb = tri + (size_t)c * NP + pb + wv * 32 + 4 * g;
            *reinterpret_cast<float4*>(tb)      = s0;
            *reinterpret_cast<float4*>(tb + 16) = s1;
        }
    }

    // ---- q,k,v,g projections: A=weights, B=pixels ----
    bf16* Os[4] = {qo, ko, vo, go};
#pragma unroll 1
    for (int m = 0; m < 4; m++) {
        const bf16* WtM = wt + m * 16384;
        fv4 acc[2][8];
#pragma unroll
        for (int n = 0; n < 8; n++) { acc[0][n] = zero; acc[1][n] = zero; }
#pragma unroll
        for (int n = 0; n < 8; n++)
#pragma unroll
            for (int kc = 0; kc < 4; kc++) {
                bfv8 bw = *reinterpret_cast<const bfv8*>(WtM + (n * 16 + c) * 128 + kc * 32 + 8 * g);
                acc[0][n] = __builtin_amdgcn_mfma_f32_16x16x32_bf16(bw, bx[0][kc], acc[0][n], 0, 0, 0);
                acc[1][n] = __builtin_amdgcn_mfma_f32_16x16x32_bf16(bw, bx[1][kc], acc[1][n], 0, 0, 0);
            }
        if (m == 3) {
#pragma unroll
            for (int n = 0; n < 8; n++) {
                float4 bgv = *reinterpret_cast<const float4*>(bg + n * 16 + 4 * g);
                float bgs[4] = {bgv.x, bgv.y, bgv.z, bgv.w};
#pragma unroll
                for (int tile = 0; tile < 2; tile++)
#pragma unroll
                    for (int r = 0; r < 4; r++) {
                        float z = acc[tile][n][r] + bgs[r];
                        acc[tile][n][r] = 1.f / (1.f + __expf(-z));
                    }
            }
        }
        bf16* O = Os[m];
#pragma unroll
        for (int tile = 0; tile < 2; tile++)
#pragma unroll
            for (int n = 0; n < 8; n++) {
                uint2 pk;
                pk.x = (unsigned)bfbits(acc[tile][n][0]) | ((unsigned)bfbits(acc[tile][n][1]) << 16);
                pk.y = (unsigned)bfbits(acc[tile][n][2]) | ((unsigned)bfbits(acc[tile][n][3]) << 16);
                *reinterpret_cast<uint2*>(O + (pb + wv * 32 + tile * 16 + c) * HC + n * 16 + 4 * g) = pk;
            }
    }
}

// ---------------- K2: flash-style MFMA attention ----------------
// v3: online softmax (defer-max THR=8) -> only one 16-key score tile live.
// PV via v_mfma_f32_16x16x16_bf16: its B-frag layout equals the QK D-layout,
// so P goes register->MFMA with zero shuffles / zero P-LDS.
// Register state ~50 VGPR, LDS 20992 B -> ~7 blocks/CU.
__global__ __launch_bounds__(256) void k_attn(
    const bf16* __restrict__ qi, const bf16* __restrict__ ki, const bf16* __restrict__ vi,
    const bf16* __restrict__ gi, const float* __restrict__ mask, const float* __restrict__ tri,
    bf16* __restrict__ oo)
{
    __shared__ unsigned short Vt[32 * 328];   // V^T [d][key], pad 8 shorts = 20992 B

    const int t = threadIdx.x;
    const int w = t >> 6, lane = t & 63, g = lane >> 4, c = lane & 15;

    // XCD-aware bijective remap (kept: FETCH_SIZE == unique footprint)
    const int r_ = blockIdx.x & 7, pos = blockIdx.x >> 3;
    const int qb5 = pos % 5;
    const int ihh = (pos / 5) * 8 + r_;
    const int h = ihh & 3, i = ihh >> 2;
    const int qb = qb5 * 64 + w * 16;
    const size_t rowbase = (size_t)i * NN;

    // ---- stage V^T: thread = (key-pair, d-octet), packed pair words ----
    unsigned* VtW = reinterpret_cast<unsigned*>(Vt);
#pragma unroll
    for (int it = 0; it < 3; it++) {
        int idx = it * 256 + t;
        if (idx < 640) {
            int kp = idx >> 2, oct = idx & 3, d0 = oct * 8;
            const uint4 va = *reinterpret_cast<const uint4*>(vi + (rowbase + 2 * kp) * HC + h * CHD + d0);
            const uint4 vb = *reinterpret_cast<const uint4*>(vi + (rowbase + 2 * kp + 1) * HC + h * CHD + d0);
            unsigned a4[4] = {va.x, va.y, va.z, va.w};
            unsigned b4[4] = {vb.x, vb.y, vb.z, vb.w};
#pragma unroll
            for (int u2 = 0; u2 < 4; u2++) {
                int d_e = d0 + 2 * u2, d_o = d_e + 1;
                VtW[d_e * 164 + kp] = (a4[u2] & 0xffffu) | ((b4[u2] & 0xffffu) << 16);
                VtW[d_o * 164 + kp] = (a4[u2] >> 16)     | ((b4[u2] >> 16) << 16);
            }
        }
    }

    bfv8 bq = *reinterpret_cast<const bfv8*>(qi + (rowbase + qb + c) * HC + h * CHD + 8 * g);

    __syncthreads();

    const float* maskrow = mask + (size_t)i * NN;
    const float* trirow  = tri + (size_t)h * NP + (size_t)(qb + c) * NN;
    const unsigned short* Vr0 = &Vt[c * 328];
    const unsigned short* Vr1 = &Vt[(16 + c) * 328];

    fv4 zero = {0.f, 0.f, 0.f, 0.f};
    fv4 o0 = zero, o1 = zero;
    float m_run = -3.0e38f, sum = 0.f;

#pragma unroll
    for (int kt = 0; kt < 20; kt++) {
        const int kbase = kt * 16;
        bfv8 ak = *reinterpret_cast<const bfv8*>(ki + (rowbase + kbase + c) * HC + h * CHD + 8 * g);
        fv4 sa = __builtin_amdgcn_mfma_f32_16x16x32_bf16(ak, bq, zero, 0, 0, 0);
        float4 mk = *reinterpret_cast<const float4*>(maskrow + kbase + 4 * g);
        float4 tr = *reinterpret_cast<const float4*>(trirow + kbase + 4 * g);
        float s0 = sa[0] + tr.x + fmaf(1.0e9f, mk.x, -1.0e9f);
        float s1 = sa[1] + tr.y + fmaf(1.0e9f, mk.y, -1.0e9f);
        float s2 = sa[2] + tr.z + fmaf(1.0e9f, mk.z, -1.0e9f);
        float s3 = sa[3] + tr.w + fmaf(1.0e9f, mk.w, -1.0e9f);

        // tile max over k (r within lane, then across the 4 g-groups)
        float mt = fmaxf(fmaxf(s0, s1), fmaxf(s2, s3));
        mt = fmaxf(mt, __shfl_xor(mt, 16, 64));
        mt = fmaxf(mt, __shfl_xor(mt, 32, 64));

        // defer-max (T13): rescale only when max grows by > 8
        if (!__all(mt <= m_run + 8.f)) {
            float mnew = fmaxf(m_run, mt);
            float f = __expf(m_run - mnew);   // exp(-3e38-x) underflows to 0: safe init
            sum *= f;
#pragma unroll
            for (int r = 0; r < 4; r++) { o0[r] *= f; o1[r] *= f; }
            m_run = mnew;
        }

        float p0 = __expf(s0 - m_run);
        float p1 = __expf(s1 - m_run);
        float p2 = __expf(s2 - m_run);
        float p3 = __expf(s3 - m_run);
        sum += (p0 + p1) + (p2 + p3);

        union { unsigned u[2]; bsv4 v; } pk;
        pk.u[0] = (unsigned)bfbits(p0) | ((unsigned)bfbits(p1) << 16);
        pk.u[1] = (unsigned)bfbits(p2) | ((unsigned)bfbits(p3) << 16);

        union { uint2 u; bsv4 v; } a0u, a1u;
        a0u.u = *reinterpret_cast<const uint2*>(Vr0 + kbase + 4 * g);
        a1u.u = *reinterpret_cast<const uint2*>(Vr1 + kbase + 4 * g);

        o0 = mfma16x16x16(a0u.v, pk.v, o0);
        o1 = mfma16x16x16(a1u.v, pk.v, o1);
    }

    // MFMA-dest -> VALU hazard guard for the inline-asm accumulators
    asm volatile("s_nop 7" :::);
    asm volatile("s_nop 7" :::);

    sum += __shfl_xor(sum, 16, 64);
    sum += __shfl_xor(sum, 32, 64);
    float linv = 1.f / sum;

    size_t obase = (rowbase + qb + c) * HC + h * CHD;
#pragma unroll
    for (int mt2 = 0; mt2 < 2; mt2++) {
        fv4 oc = mt2 ? o1 : o0;
        int d0 = mt2 * 16 + 4 * g;
        uint2 gg = *reinterpret_cast<const uint2*>(gi + obase + d0);
        float gf0 = __uint_as_float(gg.x << 16);
        float gf1 = __uint_as_float(gg.x & 0xffff0000u);
        float gf2 = __uint_as_float(gg.y << 16);
        float gf3 = __uint_as_float(gg.y & 0xffff0000u);
        uint2 st;
        st.x = (unsigned)bfbits(oc[0] * linv * gf0) | ((unsigned)bfbits(oc[1] * linv * gf1) << 16);
        st.y = (unsigned)bfbits(oc[2] * linv * gf2) | ((unsigned)bfbits(oc[3] * linv * gf3) << 16);
        *reinterpret_cast<uint2*>(oo + obase + d0) = st;
    }
}

// ---------------- K3: MFMA output projection (fp32 out, float4 stores) ----------------
__global__ __launch_bounds__(256) void k_out(
    const bf16* __restrict__ oi, const bf16* __restrict__ wot, const float* __restrict__ bo,
    float* __restrict__ outp)
{
    const int t = threadIdx.x;
    const int wv = t >> 6, lane = t & 63, g = lane >> 4, c = lane & 15;
    const size_t pb = (size_t)blockIdx.x * 64;

    bfv8 bx[4];
#pragma unroll
    for (int kc = 0; kc < 4; kc++)
        bx[kc] = *reinterpret_cast<const bfv8*>(oi + (pb + wv * 16 + c) * HC + kc * 32 + 8 * g);

    fv4 zero = {0.f, 0.f, 0.f, 0.f};
    fv4 acc[8];
#pragma unroll
    for (int n = 0; n < 8; n++) acc[n] = zero;
#pragma unroll
    for (int n = 0; n < 8; n++)
#pragma unroll
        for (int kc = 0; kc < 4; kc++) {
            bfv8 bw = *reinterpret_cast<const bfv8*>(wot + (n * 16 + c) * 128 + kc * 32 + 8 * g);
            acc[n] = __builtin_amdgcn_mfma_f32_16x16x32_bf16(bw, bx[kc], acc[n], 0, 0, 0);
        }
#pragma unroll
    for (int n = 0; n < 8; n++) {
        float4 b4 = *reinterpret_cast<const float4*>(bo + n * 16 + 4 * g);
        float4 st;
        st.x = acc[n][0] + b4.x;
        st.y = acc[n][1] + b4.y;
        st.z = acc[n][2] + b4.z;
        st.w = acc[n][3] + b4.w;
        *reinterpret_cast<float4*>(outp + (pb + wv * 16 + c) * CC + n * 16 + 4 * g) = st;
    }
}

extern "C" void kernel_launch(void* const* d_in, const int* in_sizes, int n_in,
                              void* d_out, int out_size, void* d_ws, size_t ws_size,
                              hipStream_t stream) {
    const float* x      = (const float*)d_in[0];
    const float* mask   = (const float*)d_in[1];
    const float* ln_g   = (const float*)d_in[2];
    const float* ln_b   = (const float*)d_in[3];
    const float* w_bias = (const float*)d_in[4];
    const float* wq     = (const float*)d_in[5];
    const float* wk     = (const float*)d_in[6];
    const float* wv     = (const float*)d_in[7];
    const float* wg     = (const float*)d_in[8];
    const float* bg     = (const float*)d_in[9];
    const float* wo     = (const float*)d_in[10];
    const float* bo     = (const float*)d_in[11];
    float* outp = (float*)d_out;

    bf16* qws = (bf16*)d_ws;
    bf16* kws = qws + (size_t)NP*HC;
    bf16* vws = kws + (size_t)NP*HC;
    bf16* gws = vws + (size_t)NP*HC;
    bf16* ows = gws + (size_t)NP*HC;
    float* tri = (float*)(ows + (size_t)NP*HC);
    bf16* wt  = (bf16*)(tri + (size_t)NP*HH);
    bf16* wot = wt + 4 * 16384;
    bf16* wtb = wot + 16384;

    hipLaunchKernelGGL(k_wconv, dim3(6), dim3(256), 0, stream,
                       wq, wk, wv, wg, wo, w_bias, wt, wot, wtb);
    hipLaunchKernelGGL(k_proj, dim3(NP/128), dim3(256), 0, stream,
                       x, ln_g, ln_b, wt, wtb, bg, qws, kws, vws, gws, tri);
    hipLaunchKernelGGL(k_attn, dim3(6400), dim3(256), 0, stream,
                       qws, kws, vws, gws, mask, tri, ows);
    hipLaunchKernelGGL(k_out, dim3(NP/64), dim3(256), 0, stream,
                       ows, wot, bo, outp);
}